// Round 4
// baseline (410.885 us; speedup 1.0000x reference)
//
#include <hip/hip_runtime.h>
#include <hip/hip_fp16.h>
#include <math.h>

#define BLK 256
#define NBINS_RES 27            // bin grid 27^3 = 19683 bins (~106 pts/bin)
#define HIST_N 32768            // padded to 1024*32 for the scan kernel

typedef float f2 __attribute__((ext_vector_type(2)));
typedef unsigned int uint;
typedef unsigned int uint4v __attribute__((ext_vector_type(4), aligned(8)));
typedef unsigned int uint2v __attribute__((ext_vector_type(2)));

__device__ __forceinline__ f2 cvt2(uint u) {
    __half2 h = *reinterpret_cast<__half2*>(&u);
    return (f2){ __low2float(h), __high2float(h) };
}
__device__ __forceinline__ f2 leaky2(f2 x) {
    return (f2){ fmaxf(x[0], 0.2f * x[0]), fmaxf(x[1], 0.2f * x[1]) };
}
__device__ __forceinline__ int bin_key(float dx, float dy, float dz) {
    int kx = min(NBINS_RES - 1, max(0, (int)(dx * (float)NBINS_RES)));
    int ky = min(NBINS_RES - 1, max(0, (int)(dy * (float)NBINS_RES)));
    int kz = min(NBINS_RES - 1, max(0, (int)(dz * (float)NBINS_RES)));
    return (kx * NBINS_RES + ky) * NBINS_RES + kz;
}

// ---------- sort passes ----------
__global__ __launch_bounds__(256) void zero_hist_kernel(uint* __restrict__ hist) {
    hist[blockIdx.x * 256 + threadIdx.x] = 0u;
}

__global__ __launch_bounds__(256) void hist_kernel(const float* __restrict__ dirs,
                                                   uint* __restrict__ hist, int n) {
    const int i = blockIdx.x * 256 + threadIdx.x;
    if (i >= n) return;
    atomicAdd(&hist[bin_key(dirs[3 * i], dirs[3 * i + 1], dirs[3 * i + 2])], 1u);
}

// single block, 1024 threads: in-place exclusive scan of hist[0..32767]
__global__ __launch_bounds__(1024) void scan_kernel(uint* __restrict__ hist) {
    __shared__ uint s[1024];
    const int t = threadIdx.x;
    const int base = t * 32;
    uint sum = 0;
    #pragma unroll 4
    for (int e = 0; e < 32; e++) sum += hist[base + e];
    s[t] = sum;
    __syncthreads();
    for (int off = 1; off < 1024; off <<= 1) {
        uint v = (t >= off) ? s[t - off] : 0u;
        __syncthreads();
        s[t] += v;
        __syncthreads();
    }
    uint run = s[t] - sum;   // exclusive base of this chunk
    for (int e = 0; e < 32; e++) {
        uint c = hist[base + e];
        hist[base + e] = run;
        run += c;
    }
}

__global__ __launch_bounds__(256) void scatter_kernel(const float* __restrict__ dirs,
                                                      uint* __restrict__ cursor,
                                                      float4* __restrict__ rec, int n) {
    const int i = blockIdx.x * 256 + threadIdx.x;
    if (i >= n) return;
    float dx = dirs[3 * i], dy = dirs[3 * i + 1], dz = dirs[3 * i + 2];
    uint pos = atomicAdd(&cursor[bin_key(dx, dy, dz)], 1u);
    rec[pos] = make_float4(dx, dy, dz, __uint_as_float((uint)i));
}

// grid fp32 [4][32768][4] -> fp16 same layout (8B/entry)
__global__ __launch_bounds__(256) void repack_kernel(const float* __restrict__ g,
                                                     __half* __restrict__ h) {
    const int i = blockIdx.x * 256 + threadIdx.x;   // 131072 float4 groups
    float4 v = reinterpret_cast<const float4*>(g)[i];
    __half2 h0 = __floats2half2_rn(v.x, v.y);
    __half2 h1 = __floats2half2_rn(v.z, v.w);
    uint2 u;
    u.x = *reinterpret_cast<uint*>(&h0);
    u.y = *reinterpret_cast<uint*>(&h1);
    reinterpret_cast<uint2*>(h)[i] = u;
}

// ---------- shared device body: encode + MLP ----------
__device__ __forceinline__ void encode_mlp(
    float dx, float dy, float dz,
    const __half* __restrict__ grid16,
    const float* sW1, const float* sW2, const float* sW3, const float* sW4,
    const float* sb1, const float* sb2, const float* sb3, const float* sb4,
    float& o0, float& o1, float& o2)
{
    f2 fe01[4], fe23[4];
    #pragma unroll
    for (int l = 0; l < 4; l++) {
        const int res = (l == 0) ? 16 : (l == 1) ? 24 : (l == 2) ? 36 : 54;
        const int R1 = res + 1;
        float px = dx * (float)res, py = dy * (float)res, pz = dz * (float)res;
        float fpx = floorf(px), fpy = floorf(py), fpz = floorf(pz);
        float fx = px - fpx, fy = py - fpy, fz = pz - fpz;
        int x0 = (int)fpx, y0 = (int)fpy, z0 = (int)fpz;
        int x0c = min(max(x0, 0), res), x1c = min(max(x0 + 1, 0), res);
        int y0c = min(max(y0, 0), res), y1c = min(max(y0 + 1, 0), res);
        int z0c = min(max(z0, 0), res), z1c = min(max(z0 + 1, 0), res);
        float wx0 = 1.f - fx, wx1 = fx;
        float wyz[4] = { (1.f - fy) * (1.f - fz), (1.f - fy) * fz,
                         fy * (1.f - fz),         fy * fz };          // q=(cj<<1)|ck
        f2 a01 = (f2)(0.f), a23 = (f2)(0.f);

        if (l < 2) {
            uint bo[4];
            bo[0] = (uint)(R1 * (y0c + R1 * z0c));
            bo[1] = (uint)(R1 * (y0c + R1 * z1c));
            bo[2] = (uint)(R1 * (y1c + R1 * z0c));
            bo[3] = (uint)(R1 * (y1c + R1 * z1c));
            const bool xdup = (x1c == x0c);
            const float ex0 = xdup ? (wx0 + wx1) : wx0;
            const float ex1 = xdup ? 0.f : wx1;
            const char* base = (const char*)grid16 + (size_t)l * 262144;
            uint4v v[4];
            #pragma unroll
            for (int q = 0; q < 4; q++)
                v[q] = *reinterpret_cast<const uint4v*>(base + (size_t)(bo[q] + (uint)x0c) * 8u);
            #pragma unroll
            for (int q = 0; q < 4; q++) {
                const float w0 = ex0 * wyz[q], w1 = ex1 * wyz[q];
                a01 += w0 * cvt2(v[q].x) + w1 * cvt2(v[q].z);
                a23 += w0 * cvt2(v[q].y) + w1 * cvt2(v[q].w);
            }
        } else {
            const uint ty0 = (uint)y0c * 2654435761u, ty1 = (uint)y1c * 2654435761u;
            const uint tz0 = (uint)z0c * 805459861u,  tz1 = (uint)z1c * 805459861u;
            const uint hx0 = (uint)x0c, hx1 = (uint)x1c;
            uint idx[8];
            idx[0] = (hx0 ^ ty0 ^ tz0) & 32767u;
            idx[1] = (hx0 ^ ty0 ^ tz1) & 32767u;
            idx[2] = (hx0 ^ ty1 ^ tz0) & 32767u;
            idx[3] = (hx0 ^ ty1 ^ tz1) & 32767u;
            idx[4] = (hx1 ^ ty0 ^ tz0) & 32767u;
            idx[5] = (hx1 ^ ty0 ^ tz1) & 32767u;
            idx[6] = (hx1 ^ ty1 ^ tz0) & 32767u;
            idx[7] = (hx1 ^ ty1 ^ tz1) & 32767u;
            const char* base = (const char*)grid16 + (size_t)l * 262144;
            uint2v v[8];
            #pragma unroll
            for (int c = 0; c < 8; c++)
                v[c] = *reinterpret_cast<const uint2v*>(base + (size_t)idx[c] * 8u);
            #pragma unroll
            for (int c = 0; c < 8; c++) {
                const float w = ((c & 4) ? (1.f - wx0) : wx0) * wyz[c & 3];
                a01 += w * cvt2(v[c].x);
                a23 += w * cvt2(v[c].y);
            }
        }
        fe01[l] = a01;
        fe23[l] = a23;
    }

    float fs[16];
    #pragma unroll
    for (int l = 0; l < 4; l++) {
        fs[4 * l + 0] = fe01[l][0];
        fs[4 * l + 1] = fe01[l][1];
        fs[4 * l + 2] = fe23[l][0];
        fs[4 * l + 3] = fe23[l][1];
    }

    f2 a1[16];
    #pragma unroll
    for (int jj = 0; jj < 16; jj++) a1[jj] = *reinterpret_cast<const f2*>(&sb1[2 * jj]);
    #pragma unroll
    for (int ii = 0; ii < 16; ii++) {
        const float f = fs[ii];
        #pragma unroll
        for (int jj = 0; jj < 8; jj++) {
            float4 w4 = *reinterpret_cast<const float4*>(&sW1[ii * 32 + 4 * jj]);
            a1[2 * jj + 0] += f * (f2){ w4.x, w4.y };
            a1[2 * jj + 1] += f * (f2){ w4.z, w4.w };
        }
    }
    #pragma unroll
    for (int jj = 0; jj < 16; jj++) a1[jj] = leaky2(a1[jj]);

    f2 a2[8];
    #pragma unroll
    for (int jj = 0; jj < 8; jj++) a2[jj] = *reinterpret_cast<const f2*>(&sb2[2 * jj]);
    #pragma unroll
    for (int ii = 0; ii < 32; ii++) {
        const float f = a1[ii >> 1][ii & 1];
        #pragma unroll
        for (int jj = 0; jj < 4; jj++) {
            float4 w4 = *reinterpret_cast<const float4*>(&sW2[ii * 16 + 4 * jj]);
            a2[2 * jj + 0] += f * (f2){ w4.x, w4.y };
            a2[2 * jj + 1] += f * (f2){ w4.z, w4.w };
        }
    }
    #pragma unroll
    for (int jj = 0; jj < 8; jj++) a2[jj] = leaky2(a2[jj]);

    f2 a3[4];
    #pragma unroll
    for (int jj = 0; jj < 4; jj++) a3[jj] = *reinterpret_cast<const f2*>(&sb3[2 * jj]);
    #pragma unroll
    for (int ii = 0; ii < 16; ii++) {
        const float f = a2[ii >> 1][ii & 1];
        #pragma unroll
        for (int jj = 0; jj < 2; jj++) {
            float4 w4 = *reinterpret_cast<const float4*>(&sW3[ii * 8 + 4 * jj]);
            a3[2 * jj + 0] += f * (f2){ w4.x, w4.y };
            a3[2 * jj + 1] += f * (f2){ w4.z, w4.w };
        }
    }
    #pragma unroll
    for (int jj = 0; jj < 4; jj++) a3[jj] = leaky2(a3[jj]);

    o0 = sb4[0]; o1 = sb4[1]; o2 = sb4[2];
    #pragma unroll
    for (int ii = 0; ii < 8; ii++) {
        const float f = a3[ii >> 1][ii & 1];
        o0 += f * sW4[ii * 3 + 0];
        o1 += f * sW4[ii * 3 + 1];
        o2 += f * sW4[ii * 3 + 2];
    }
}

#define STAGE_WEIGHTS()                                                      \
    __shared__ __align__(16) float sW1[16 * 32];                             \
    __shared__ __align__(16) float sW2[32 * 16];                             \
    __shared__ __align__(16) float sW3[16 * 8];                              \
    __shared__ __align__(16) float sW4[8 * 3];                               \
    __shared__ __align__(16) float sb1[32];                                  \
    __shared__ __align__(16) float sb2[16];                                  \
    __shared__ __align__(16) float sb3[8];                                   \
    __shared__ __align__(16) float sb4[4];                                   \
    {                                                                        \
        const int tt = threadIdx.x;                                          \
        for (int q = tt; q < 512; q += BLK) { sW1[q] = W1[q]; sW2[q] = W2[q]; } \
        if (tt < 128) sW3[tt] = W3[tt];                                      \
        if (tt < 24)  sW4[tt] = W4[tt];                                      \
        if (tt < 32)  sb1[tt] = b1[tt];                                      \
        if (tt < 16)  sb2[tt] = b2[tt];                                      \
        if (tt < 8)   sb3[tt] = b3[tt];                                      \
        if (tt < 3)   sb4[tt] = b4[tt];                                      \
        __syncthreads();                                                     \
    }

// ---------- main fused kernel (sorted records) ----------
__global__ __launch_bounds__(BLK, 3) void ngp_main(
    const float4* __restrict__ rec,
    const __half* __restrict__ grid16,
    const float* __restrict__ W1, const float* __restrict__ b1,
    const float* __restrict__ W2, const float* __restrict__ b2,
    const float* __restrict__ W3, const float* __restrict__ b3,
    const float* __restrict__ W4, const float* __restrict__ b4,
    float* __restrict__ out, int n)
{
    STAGE_WEIGHTS();
    const int t = blockIdx.x * BLK + threadIdx.x;
    if (t >= n) return;
    float4 r = rec[t];
    float o0, o1, o2;
    encode_mlp(r.x, r.y, r.z, grid16, sW1, sW2, sW3, sW4, sb1, sb2, sb3, sb4, o0, o1, o2);
    const uint idx = __float_as_uint(r.w);
    float3 ov = { tanhf(o0), tanhf(o1), tanhf(o2) };
    *reinterpret_cast<float3*>(out + 3 * (size_t)idx) = ov;
}

// ---------- fallback: unsorted direct (fp16 grid) ----------
__global__ __launch_bounds__(BLK, 3) void ngp_direct(
    const float* __restrict__ dirs,
    const __half* __restrict__ grid16,
    const float* __restrict__ W1, const float* __restrict__ b1,
    const float* __restrict__ W2, const float* __restrict__ b2,
    const float* __restrict__ W3, const float* __restrict__ b3,
    const float* __restrict__ W4, const float* __restrict__ b4,
    float* __restrict__ out, int n)
{
    STAGE_WEIGHTS();
    const int i = blockIdx.x * BLK + threadIdx.x;
    if (i >= n) return;
    float o0, o1, o2;
    encode_mlp(dirs[3 * i], dirs[3 * i + 1], dirs[3 * i + 2], grid16,
               sW1, sW2, sW3, sW4, sb1, sb2, sb3, sb4, o0, o1, o2);
    out[3 * i + 0] = tanhf(o0);
    out[3 * i + 1] = tanhf(o1);
    out[3 * i + 2] = tanhf(o2);
}

extern "C" void kernel_launch(void* const* d_in, const int* in_sizes, int n_in,
                              void* d_out, int out_size, void* d_ws, size_t ws_size,
                              hipStream_t stream) {
    const float* dirs = (const float*)d_in[0];
    const float* grid = (const float*)d_in[1];
    const float* W1 = (const float*)d_in[2];
    const float* b1 = (const float*)d_in[3];
    const float* W2 = (const float*)d_in[4];
    const float* b2 = (const float*)d_in[5];
    const float* W3 = (const float*)d_in[6];
    const float* b3 = (const float*)d_in[7];
    const float* W4 = (const float*)d_in[8];
    const float* b4 = (const float*)d_in[9];
    float* out = (float*)d_out;

    const int n = in_sizes[0] / 3;
    const int nblocks = (n + BLK - 1) / BLK;

    const size_t off_grid16 = 0;                      // 1 MiB
    const size_t off_hist   = 1048576;                // 128 KiB (32768 u32)
    const size_t off_rec    = 1048576 + 131072;       // n*16 B
    const size_t need_full  = off_rec + (size_t)n * 16;
    const size_t need_f16   = 1048576;

    if (ws_size >= need_full) {
        __half* g16  = (__half*)((char*)d_ws + off_grid16);
        uint*   hist = (uint*)((char*)d_ws + off_hist);
        float4* rec  = (float4*)((char*)d_ws + off_rec);

        hipLaunchKernelGGL(repack_kernel, dim3(512), dim3(256), 0, stream, grid, g16);
        hipLaunchKernelGGL(zero_hist_kernel, dim3(HIST_N / 256), dim3(256), 0, stream, hist);
        hipLaunchKernelGGL(hist_kernel, dim3((n + 255) / 256), dim3(256), 0, stream, dirs, hist, n);
        hipLaunchKernelGGL(scan_kernel, dim3(1), dim3(1024), 0, stream, hist);
        hipLaunchKernelGGL(scatter_kernel, dim3((n + 255) / 256), dim3(256), 0, stream, dirs, hist, rec, n);
        hipLaunchKernelGGL(ngp_main, dim3(nblocks), dim3(BLK), 0, stream,
                           rec, g16, W1, b1, W2, b2, W3, b3, W4, b4, out, n);
    } else if (ws_size >= need_f16) {
        __half* g16 = (__half*)d_ws;
        hipLaunchKernelGGL(repack_kernel, dim3(512), dim3(256), 0, stream, grid, g16);
        hipLaunchKernelGGL(ngp_direct, dim3(nblocks), dim3(BLK), 0, stream,
                           dirs, g16, W1, b1, W2, b2, W3, b3, W4, b4, out, n);
    }
}

// Round 5
// 189.785 us; speedup vs baseline: 2.1650x; 2.1650x over previous
//
#include <hip/hip_runtime.h>
#include <hip/hip_fp16.h>
#include <math.h>

#define BLK 256

typedef float f2 __attribute__((ext_vector_type(2)));
typedef unsigned int uint;
typedef unsigned int uint4v __attribute__((ext_vector_type(4), aligned(8)));
typedef unsigned int uint2v __attribute__((ext_vector_type(2)));

__device__ __forceinline__ f2 cvt2(uint u) {
    __half2 h = *reinterpret_cast<__half2*>(&u);
    return (f2){ __low2float(h), __high2float(h) };
}

__device__ __forceinline__ float fast_tanh(float x) {
    x = fminf(15.f, fmaxf(-15.f, x));
    float e = __expf(2.0f * x);                       // v_mul + v_exp
    return (e - 1.0f) * __builtin_amdgcn_rcpf(e + 1.0f);
}

// grid fp32 [4][32768][4] -> fp16 same layout (8B/entry)
__global__ __launch_bounds__(256) void repack_kernel(const float* __restrict__ g,
                                                     __half* __restrict__ h) {
    const int i = blockIdx.x * 256 + threadIdx.x;   // 131072 float4 groups
    float4 v = reinterpret_cast<const float4*>(g)[i];
    __half2 h0 = __floats2half2_rn(v.x, v.y);
    __half2 h1 = __floats2half2_rn(v.z, v.w);
    uint2 u;
    u.x = *reinterpret_cast<uint*>(&h0);
    u.y = *reinterpret_cast<uint*>(&h1);
    reinterpret_cast<uint2*>(h)[i] = u;
}

// F16=1: gathers from fp16 repacked grid in ws. F16=0: fp32 grid directly.
template<int F16>
__global__ __launch_bounds__(BLK) void ngp_direct(
    const float* __restrict__ dirs,
    const float* __restrict__ grid32,
    const __half* __restrict__ grid16,
    const float* __restrict__ W1, const float* __restrict__ b1,
    const float* __restrict__ W2, const float* __restrict__ b2,
    const float* __restrict__ W3, const float* __restrict__ b3,
    const float* __restrict__ W4, const float* __restrict__ b4,
    float* __restrict__ out, int n)
{
    const int i = blockIdx.x * BLK + threadIdx.x;
    if (i >= n) return;

    const float dx = dirs[3 * i + 0];
    const float dy = dirs[3 * i + 1];
    const float dz = dirs[3 * i + 2];

    // ---------------- hash-grid encode ----------------
    float fs[16];
    #pragma unroll
    for (int l = 0; l < 4; l++) {
        const int res = (l == 0) ? 16 : (l == 1) ? 24 : (l == 2) ? 36 : 54;
        const int R1 = res + 1;
        float px = dx * (float)res, py = dy * (float)res, pz = dz * (float)res;
        float fpx = floorf(px), fpy = floorf(py), fpz = floorf(pz);
        float fx = px - fpx, fy = py - fpy, fz = pz - fpz;
        int x0 = (int)fpx, y0 = (int)fpy, z0 = (int)fpz;
        int x0c = min(max(x0, 0), res), x1c = min(max(x0 + 1, 0), res);
        int y0c = min(max(y0, 0), res), y1c = min(max(y0 + 1, 0), res);
        int z0c = min(max(z0, 0), res), z1c = min(max(z0 + 1, 0), res);
        float wx0 = 1.f - fx, wx1 = fx;
        float wyz[4] = { (1.f - fy) * (1.f - fz), (1.f - fy) * fz,
                         fy * (1.f - fz),         fy * fz };          // q=(cj<<1)|ck
        f2 a01 = (f2)(0.f), a23 = (f2)(0.f);

        if (l < 2) {
            // dense: idx = x + R1*(y + R1*z); x-pairs contiguous
            uint bo[4];
            bo[0] = (uint)(R1 * (y0c + R1 * z0c));
            bo[1] = (uint)(R1 * (y0c + R1 * z1c));
            bo[2] = (uint)(R1 * (y1c + R1 * z0c));
            bo[3] = (uint)(R1 * (y1c + R1 * z1c));
            if (F16) {
                const bool xdup = (x1c == x0c);
                const float ex0 = xdup ? (wx0 + wx1) : wx0;
                const float ex1 = xdup ? 0.f : wx1;
                const char* base = (const char*)grid16 + (size_t)l * 262144;
                uint4v v[4];
                #pragma unroll
                for (int q = 0; q < 4; q++)
                    v[q] = *reinterpret_cast<const uint4v*>(base + (size_t)(bo[q] + (uint)x0c) * 8u);
                #pragma unroll
                for (int q = 0; q < 4; q++) {
                    const float w0 = ex0 * wyz[q], w1 = ex1 * wyz[q];
                    a01 += w0 * cvt2(v[q].x) + w1 * cvt2(v[q].z);
                    a23 += w0 * cvt2(v[q].y) + w1 * cvt2(v[q].w);
                }
            } else {
                const float* base = grid32 + (size_t)l * 131072;
                float4 v[8];
                #pragma unroll
                for (int c = 0; c < 8; c++) {
                    uint idx = ((c & 4) ? (uint)x1c : (uint)x0c) + bo[c & 3];
                    v[c] = *reinterpret_cast<const float4*>(base + idx * 4u);
                }
                #pragma unroll
                for (int c = 0; c < 8; c++) {
                    const float w = ((c & 4) ? wx1 : wx0) * wyz[c & 3];
                    a01 += w * (f2){ v[c].x, v[c].y };
                    a23 += w * (f2){ v[c].z, v[c].w };
                }
            }
        } else {
            const uint ty0 = (uint)y0c * 2654435761u, ty1 = (uint)y1c * 2654435761u;
            const uint tz0 = (uint)z0c * 805459861u,  tz1 = (uint)z1c * 805459861u;
            const uint hx0 = (uint)x0c, hx1 = (uint)x1c;
            uint idx[8];
            idx[0] = (hx0 ^ ty0 ^ tz0) & 32767u;
            idx[1] = (hx0 ^ ty0 ^ tz1) & 32767u;
            idx[2] = (hx0 ^ ty1 ^ tz0) & 32767u;
            idx[3] = (hx0 ^ ty1 ^ tz1) & 32767u;
            idx[4] = (hx1 ^ ty0 ^ tz0) & 32767u;
            idx[5] = (hx1 ^ ty0 ^ tz1) & 32767u;
            idx[6] = (hx1 ^ ty1 ^ tz0) & 32767u;
            idx[7] = (hx1 ^ ty1 ^ tz1) & 32767u;
            if (F16) {
                const char* base = (const char*)grid16 + (size_t)l * 262144;
                uint2v v[8];
                #pragma unroll
                for (int c = 0; c < 8; c++)
                    v[c] = *reinterpret_cast<const uint2v*>(base + (size_t)idx[c] * 8u);
                #pragma unroll
                for (int c = 0; c < 8; c++) {
                    const float w = ((c & 4) ? wx1 : wx0) * wyz[c & 3];
                    a01 += w * cvt2(v[c].x);
                    a23 += w * cvt2(v[c].y);
                }
            } else {
                const float* base = grid32 + (size_t)l * 131072;
                float4 v[8];
                #pragma unroll
                for (int c = 0; c < 8; c++)
                    v[c] = *reinterpret_cast<const float4*>(base + idx[c] * 4u);
                #pragma unroll
                for (int c = 0; c < 8; c++) {
                    const float w = ((c & 4) ? wx1 : wx0) * wyz[c & 3];
                    a01 += w * (f2){ v[c].x, v[c].y };
                    a23 += w * (f2){ v[c].z, v[c].w };
                }
            }
        }
        fs[4 * l + 0] = a01[0];
        fs[4 * l + 1] = a01[1];
        fs[4 * l + 2] = a23[0];
        fs[4 * l + 3] = a23[1];
    }

    // ---------------- MLP: weights read via uniform (scalar) loads ----------------
    float h1[32];
    #pragma unroll
    for (int jj = 0; jj < 32; jj++) h1[jj] = b1[jj];
    #pragma unroll
    for (int ii = 0; ii < 16; ii++) {
        const float f = fs[ii];
        #pragma unroll
        for (int jj = 0; jj < 32; jj++) h1[jj] = fmaf(f, W1[ii * 32 + jj], h1[jj]);
    }
    #pragma unroll
    for (int jj = 0; jj < 32; jj++) h1[jj] = fmaxf(h1[jj], 0.2f * h1[jj]);

    float h2[16];
    #pragma unroll
    for (int jj = 0; jj < 16; jj++) h2[jj] = b2[jj];
    #pragma unroll
    for (int ii = 0; ii < 32; ii++) {
        const float f = h1[ii];
        #pragma unroll
        for (int jj = 0; jj < 16; jj++) h2[jj] = fmaf(f, W2[ii * 16 + jj], h2[jj]);
    }
    #pragma unroll
    for (int jj = 0; jj < 16; jj++) h2[jj] = fmaxf(h2[jj], 0.2f * h2[jj]);

    float h3[8];
    #pragma unroll
    for (int jj = 0; jj < 8; jj++) h3[jj] = b3[jj];
    #pragma unroll
    for (int ii = 0; ii < 16; ii++) {
        const float f = h2[ii];
        #pragma unroll
        for (int jj = 0; jj < 8; jj++) h3[jj] = fmaf(f, W3[ii * 8 + jj], h3[jj]);
    }
    #pragma unroll
    for (int jj = 0; jj < 8; jj++) h3[jj] = fmaxf(h3[jj], 0.2f * h3[jj]);

    float o0 = b4[0], o1 = b4[1], o2 = b4[2];
    #pragma unroll
    for (int ii = 0; ii < 8; ii++) {
        const float f = h3[ii];
        o0 = fmaf(f, W4[ii * 3 + 0], o0);
        o1 = fmaf(f, W4[ii * 3 + 1], o1);
        o2 = fmaf(f, W4[ii * 3 + 2], o2);
    }

    out[3 * i + 0] = fast_tanh(o0);
    out[3 * i + 1] = fast_tanh(o1);
    out[3 * i + 2] = fast_tanh(o2);
}

extern "C" void kernel_launch(void* const* d_in, const int* in_sizes, int n_in,
                              void* d_out, int out_size, void* d_ws, size_t ws_size,
                              hipStream_t stream) {
    const float* dirs = (const float*)d_in[0];
    const float* grid = (const float*)d_in[1];
    const float* W1 = (const float*)d_in[2];
    const float* b1 = (const float*)d_in[3];
    const float* W2 = (const float*)d_in[4];
    const float* b2 = (const float*)d_in[5];
    const float* W3 = (const float*)d_in[6];
    const float* b3 = (const float*)d_in[7];
    const float* W4 = (const float*)d_in[8];
    const float* b4 = (const float*)d_in[9];
    float* out = (float*)d_out;

    const int n = in_sizes[0] / 3;
    const int nblocks = (n + BLK - 1) / BLK;
    const size_t need16 = (size_t)4 * 32768 * 4 * sizeof(__half);   // 1 MiB

    if (ws_size >= need16) {
        __half* g16 = (__half*)d_ws;
        hipLaunchKernelGGL(repack_kernel, dim3(512), dim3(256), 0, stream, grid, g16);
        hipLaunchKernelGGL((ngp_direct<1>), dim3(nblocks), dim3(BLK), 0, stream,
                           dirs, grid, g16, W1, b1, W2, b2, W3, b3, W4, b4, out, n);
    } else {
        hipLaunchKernelGGL((ngp_direct<0>), dim3(nblocks), dim3(BLK), 0, stream,
                           dirs, grid, (const __half*)nullptr,
                           W1, b1, W2, b2, W3, b3, W4, b4, out, n);
    }
}

// Round 6
// 181.510 us; speedup vs baseline: 2.2637x; 1.0456x over previous
//
#include <hip/hip_runtime.h>
#include <hip/hip_fp16.h>
#include <math.h>

#define BLK 256

typedef float f2 __attribute__((ext_vector_type(2)));
typedef unsigned int uint;
typedef unsigned int uint4v __attribute__((ext_vector_type(4), aligned(8)));
typedef unsigned int uint2v __attribute__((ext_vector_type(2)));

__device__ __forceinline__ f2 cvt2(uint u) {
    __half2 h = *reinterpret_cast<__half2*>(&u);
    return (f2){ __low2float(h), __high2float(h) };
}
__device__ __forceinline__ f2 leaky2(f2 x) {
    return (f2){ fmaxf(x[0], 0.2f * x[0]), fmaxf(x[1], 0.2f * x[1]) };
}
__device__ __forceinline__ float fast_tanh(float x) {
    x = fminf(15.f, fmaxf(-15.f, x));
    float e = __expf(2.0f * x);
    return (e - 1.0f) * __builtin_amdgcn_rcpf(e + 1.0f);
}

// grid fp32 [4][32768][4] -> fp16 same layout (8B/entry)
__global__ __launch_bounds__(256) void repack_kernel(const float* __restrict__ g,
                                                     __half* __restrict__ h) {
    const int i = blockIdx.x * 256 + threadIdx.x;   // 131072 float4 groups
    float4 v = reinterpret_cast<const float4*>(g)[i];
    __half2 h0 = __floats2half2_rn(v.x, v.y);
    __half2 h1 = __floats2half2_rn(v.z, v.w);
    uint2 u;
    u.x = *reinterpret_cast<uint*>(&h0);
    u.y = *reinterpret_cast<uint*>(&h1);
    reinterpret_cast<uint2*>(h)[i] = u;
}

__global__ __launch_bounds__(BLK) void ngp_f16(
    const float* __restrict__ dirs,
    const __half* __restrict__ grid16,
    const float* __restrict__ W1, const float* __restrict__ b1,
    const float* __restrict__ W2, const float* __restrict__ b2,
    const float* __restrict__ W3, const float* __restrict__ b3,
    const float* __restrict__ W4, const float* __restrict__ b4,
    float* __restrict__ out, int n)
{
    const int i = blockIdx.x * BLK + threadIdx.x;
    if (i >= n) return;

    const float dx = dirs[3 * i + 0];
    const float dy = dirs[3 * i + 1];
    const float dz = dirs[3 * i + 2];

    // ================= phase 1: all 24 gather loads issued up-front =================
    float fxl[4], fyl[4], fzl[4];
    bool  xd[2];
    uint4v vd[2][4];   // dense levels 0,1: 4 x 16B (entry pair [x0c, x0c+1])
    uint2v vh[2][8];   // hashed levels 2,3: 8 x 8B

    #pragma unroll
    for (int l = 0; l < 2; l++) {
        const int res = l ? 24 : 16;
        const int R1 = res + 1;
        float px = dx * (float)res, py = dy * (float)res, pz = dz * (float)res;
        float fpx = floorf(px), fpy = floorf(py), fpz = floorf(pz);
        fxl[l] = px - fpx; fyl[l] = py - fpy; fzl[l] = pz - fpz;
        int x0 = (int)fpx, y0 = (int)fpy, z0 = (int)fpz;
        int x0c = min(max(x0, 0), res), x1c = min(max(x0 + 1, 0), res);
        int y0c = min(max(y0, 0), res), y1c = min(max(y0 + 1, 0), res);
        int z0c = min(max(z0, 0), res), z1c = min(max(z0 + 1, 0), res);
        xd[l] = (x1c == x0c);
        const char* base = (const char*)grid16 + (size_t)l * 262144;
        uint bo0 = (uint)(R1 * (y0c + R1 * z0c));
        uint bo1 = (uint)(R1 * (y0c + R1 * z1c));
        uint bo2 = (uint)(R1 * (y1c + R1 * z0c));
        uint bo3 = (uint)(R1 * (y1c + R1 * z1c));
        vd[l][0] = *reinterpret_cast<const uint4v*>(base + (size_t)(bo0 + (uint)x0c) * 8u);
        vd[l][1] = *reinterpret_cast<const uint4v*>(base + (size_t)(bo1 + (uint)x0c) * 8u);
        vd[l][2] = *reinterpret_cast<const uint4v*>(base + (size_t)(bo2 + (uint)x0c) * 8u);
        vd[l][3] = *reinterpret_cast<const uint4v*>(base + (size_t)(bo3 + (uint)x0c) * 8u);
    }

    #pragma unroll
    for (int l = 0; l < 2; l++) {
        const int res = l ? 54 : 36;
        float px = dx * (float)res, py = dy * (float)res, pz = dz * (float)res;
        float fpx = floorf(px), fpy = floorf(py), fpz = floorf(pz);
        fxl[2 + l] = px - fpx; fyl[2 + l] = py - fpy; fzl[2 + l] = pz - fpz;
        int x0 = (int)fpx, y0 = (int)fpy, z0 = (int)fpz;
        int x0c = min(max(x0, 0), res), x1c = min(max(x0 + 1, 0), res);
        int y0c = min(max(y0, 0), res), y1c = min(max(y0 + 1, 0), res);
        int z0c = min(max(z0, 0), res), z1c = min(max(z0 + 1, 0), res);
        const uint ty0 = (uint)y0c * 2654435761u, ty1 = (uint)y1c * 2654435761u;
        const uint tz0 = (uint)z0c * 805459861u,  tz1 = (uint)z1c * 805459861u;
        const uint hx0 = (uint)x0c, hx1 = (uint)x1c;
        const char* base = (const char*)grid16 + (size_t)(2 + l) * 262144;
        uint idx0 = (hx0 ^ ty0 ^ tz0) & 32767u;
        uint idx1 = (hx0 ^ ty0 ^ tz1) & 32767u;
        uint idx2 = (hx0 ^ ty1 ^ tz0) & 32767u;
        uint idx3 = (hx0 ^ ty1 ^ tz1) & 32767u;
        uint idx4 = (hx1 ^ ty0 ^ tz0) & 32767u;
        uint idx5 = (hx1 ^ ty0 ^ tz1) & 32767u;
        uint idx6 = (hx1 ^ ty1 ^ tz0) & 32767u;
        uint idx7 = (hx1 ^ ty1 ^ tz1) & 32767u;
        vh[l][0] = *reinterpret_cast<const uint2v*>(base + (size_t)idx0 * 8u);
        vh[l][1] = *reinterpret_cast<const uint2v*>(base + (size_t)idx1 * 8u);
        vh[l][2] = *reinterpret_cast<const uint2v*>(base + (size_t)idx2 * 8u);
        vh[l][3] = *reinterpret_cast<const uint2v*>(base + (size_t)idx3 * 8u);
        vh[l][4] = *reinterpret_cast<const uint2v*>(base + (size_t)idx4 * 8u);
        vh[l][5] = *reinterpret_cast<const uint2v*>(base + (size_t)idx5 * 8u);
        vh[l][6] = *reinterpret_cast<const uint2v*>(base + (size_t)idx6 * 8u);
        vh[l][7] = *reinterpret_cast<const uint2v*>(base + (size_t)idx7 * 8u);
    }

    // keep the load batch above all consuming VALU work
    __builtin_amdgcn_sched_barrier(0);

    // ================= phase 2: trilinear combine =================
    float fs[16];
    #pragma unroll
    for (int l = 0; l < 2; l++) {
        const float fx = fxl[l], fy = fyl[l], fz = fzl[l];
        float wyz[4] = { (1.f - fy) * (1.f - fz), (1.f - fy) * fz,
                         fy * (1.f - fz),         fy * fz };
        const float ex0 = xd[l] ? 1.0f : (1.f - fx);
        const float ex1 = xd[l] ? 0.0f : fx;
        f2 a01 = (f2)(0.f), a23 = (f2)(0.f);
        #pragma unroll
        for (int q = 0; q < 4; q++) {
            const float w0 = ex0 * wyz[q], w1 = ex1 * wyz[q];
            a01 += w0 * cvt2(vd[l][q].x) + w1 * cvt2(vd[l][q].z);
            a23 += w0 * cvt2(vd[l][q].y) + w1 * cvt2(vd[l][q].w);
        }
        fs[4 * l + 0] = a01[0];
        fs[4 * l + 1] = a01[1];
        fs[4 * l + 2] = a23[0];
        fs[4 * l + 3] = a23[1];
    }
    #pragma unroll
    for (int l = 0; l < 2; l++) {
        const float fx = fxl[2 + l], fy = fyl[2 + l], fz = fzl[2 + l];
        float wyz[4] = { (1.f - fy) * (1.f - fz), (1.f - fy) * fz,
                         fy * (1.f - fz),         fy * fz };
        const float wx0 = 1.f - fx, wx1 = fx;
        f2 a01 = (f2)(0.f), a23 = (f2)(0.f);
        #pragma unroll
        for (int c = 0; c < 8; c++) {
            const float w = ((c & 4) ? wx1 : wx0) * wyz[c & 3];
            a01 += w * cvt2(vh[l][c].x);
            a23 += w * cvt2(vh[l][c].y);
        }
        fs[8 + 4 * l + 0] = a01[0];
        fs[8 + 4 * l + 1] = a01[1];
        fs[8 + 4 * l + 2] = a23[0];
        fs[8 + 4 * l + 3] = a23[1];
    }

    // ================= phase 3: MLP in packed f2 (v_pk_fma_f32) =================
    const f2* W1v = reinterpret_cast<const f2*>(W1);
    const f2* W2v = reinterpret_cast<const f2*>(W2);
    const f2* W3v = reinterpret_cast<const f2*>(W3);
    const f2* b1v = reinterpret_cast<const f2*>(b1);
    const f2* b2v = reinterpret_cast<const f2*>(b2);
    const f2* b3v = reinterpret_cast<const f2*>(b3);

    f2 h1[16];
    #pragma unroll
    for (int jj = 0; jj < 16; jj++) h1[jj] = b1v[jj];
    #pragma unroll
    for (int ii = 0; ii < 16; ii++) {
        const f2 f = (f2){ fs[ii], fs[ii] };
        #pragma unroll
        for (int jj = 0; jj < 16; jj++) h1[jj] += f * W1v[ii * 16 + jj];
    }
    #pragma unroll
    for (int jj = 0; jj < 16; jj++) h1[jj] = leaky2(h1[jj]);

    f2 h2[8];
    #pragma unroll
    for (int jj = 0; jj < 8; jj++) h2[jj] = b2v[jj];
    #pragma unroll
    for (int ii = 0; ii < 32; ii++) {
        const float fv = h1[ii >> 1][ii & 1];
        const f2 f = (f2){ fv, fv };
        #pragma unroll
        for (int jj = 0; jj < 8; jj++) h2[jj] += f * W2v[ii * 8 + jj];
    }
    #pragma unroll
    for (int jj = 0; jj < 8; jj++) h2[jj] = leaky2(h2[jj]);

    f2 h3[4];
    #pragma unroll
    for (int jj = 0; jj < 4; jj++) h3[jj] = b3v[jj];
    #pragma unroll
    for (int ii = 0; ii < 16; ii++) {
        const float fv = h2[ii >> 1][ii & 1];
        const f2 f = (f2){ fv, fv };
        #pragma unroll
        for (int jj = 0; jj < 4; jj++) h3[jj] += f * W3v[ii * 4 + jj];
    }
    #pragma unroll
    for (int jj = 0; jj < 4; jj++) h3[jj] = leaky2(h3[jj]);

    float o0 = b4[0], o1 = b4[1], o2 = b4[2];
    #pragma unroll
    for (int ii = 0; ii < 8; ii++) {
        const float f = h3[ii >> 1][ii & 1];
        o0 = fmaf(f, W4[ii * 3 + 0], o0);
        o1 = fmaf(f, W4[ii * 3 + 1], o1);
        o2 = fmaf(f, W4[ii * 3 + 2], o2);
    }

    out[3 * i + 0] = fast_tanh(o0);
    out[3 * i + 1] = fast_tanh(o1);
    out[3 * i + 2] = fast_tanh(o2);
}

// ---------- fallback: fp32 grid directly (no workspace) ----------
__global__ __launch_bounds__(BLK) void ngp_f32(
    const float* __restrict__ dirs,
    const float* __restrict__ grid32,
    const float* __restrict__ W1, const float* __restrict__ b1,
    const float* __restrict__ W2, const float* __restrict__ b2,
    const float* __restrict__ W3, const float* __restrict__ b3,
    const float* __restrict__ W4, const float* __restrict__ b4,
    float* __restrict__ out, int n)
{
    const int i = blockIdx.x * BLK + threadIdx.x;
    if (i >= n) return;
    const float dx = dirs[3 * i], dy = dirs[3 * i + 1], dz = dirs[3 * i + 2];

    float fs[16];
    #pragma unroll
    for (int l = 0; l < 4; l++) {
        const int res = (l == 0) ? 16 : (l == 1) ? 24 : (l == 2) ? 36 : 54;
        const int R1 = res + 1;
        float px = dx * (float)res, py = dy * (float)res, pz = dz * (float)res;
        float fpx = floorf(px), fpy = floorf(py), fpz = floorf(pz);
        float fx = px - fpx, fy = py - fpy, fz = pz - fpz;
        int x0 = (int)fpx, y0 = (int)fpy, z0 = (int)fpz;
        int x0c = min(max(x0, 0), res), x1c = min(max(x0 + 1, 0), res);
        int y0c = min(max(y0, 0), res), y1c = min(max(y0 + 1, 0), res);
        int z0c = min(max(z0, 0), res), z1c = min(max(z0 + 1, 0), res);
        float wx0 = 1.f - fx, wx1 = fx;
        float wyz[4] = { (1.f - fy) * (1.f - fz), (1.f - fy) * fz,
                         fy * (1.f - fz),         fy * fz };
        f2 a01 = (f2)(0.f), a23 = (f2)(0.f);
        const float* base = grid32 + (size_t)l * 131072;
        #pragma unroll
        for (int c = 0; c < 8; c++) {
            int gx = (c & 4) ? x1c : x0c;
            int gy = ((c >> 1) & 1) ? y1c : y0c;
            int gz = (c & 1) ? z1c : z0c;
            uint idx;
            if (l < 2) idx = (uint)(gx + R1 * (gy + R1 * gz));
            else idx = ((uint)gx ^ ((uint)gy * 2654435761u) ^ ((uint)gz * 805459861u)) & 32767u;
            float4 v = *reinterpret_cast<const float4*>(base + idx * 4u);
            const float w = ((c & 4) ? wx1 : wx0) * wyz[c & 3];
            a01 += w * (f2){ v.x, v.y };
            a23 += w * (f2){ v.z, v.w };
        }
        fs[4 * l + 0] = a01[0];
        fs[4 * l + 1] = a01[1];
        fs[4 * l + 2] = a23[0];
        fs[4 * l + 3] = a23[1];
    }

    float h1[32];
    #pragma unroll
    for (int jj = 0; jj < 32; jj++) h1[jj] = b1[jj];
    #pragma unroll
    for (int ii = 0; ii < 16; ii++)
        #pragma unroll
        for (int jj = 0; jj < 32; jj++) h1[jj] = fmaf(fs[ii], W1[ii * 32 + jj], h1[jj]);
    #pragma unroll
    for (int jj = 0; jj < 32; jj++) h1[jj] = fmaxf(h1[jj], 0.2f * h1[jj]);

    float h2[16];
    #pragma unroll
    for (int jj = 0; jj < 16; jj++) h2[jj] = b2[jj];
    #pragma unroll
    for (int ii = 0; ii < 32; ii++)
        #pragma unroll
        for (int jj = 0; jj < 16; jj++) h2[jj] = fmaf(h1[ii], W2[ii * 16 + jj], h2[jj]);
    #pragma unroll
    for (int jj = 0; jj < 16; jj++) h2[jj] = fmaxf(h2[jj], 0.2f * h2[jj]);

    float h3[8];
    #pragma unroll
    for (int jj = 0; jj < 8; jj++) h3[jj] = b3[jj];
    #pragma unroll
    for (int ii = 0; ii < 16; ii++)
        #pragma unroll
        for (int jj = 0; jj < 8; jj++) h3[jj] = fmaf(h2[ii], W3[ii * 8 + jj], h3[jj]);
    #pragma unroll
    for (int jj = 0; jj < 8; jj++) h3[jj] = fmaxf(h3[jj], 0.2f * h3[jj]);

    float o0 = b4[0], o1 = b4[1], o2 = b4[2];
    #pragma unroll
    for (int ii = 0; ii < 8; ii++) {
        o0 = fmaf(h3[ii], W4[ii * 3 + 0], o0);
        o1 = fmaf(h3[ii], W4[ii * 3 + 1], o1);
        o2 = fmaf(h3[ii], W4[ii * 3 + 2], o2);
    }
    out[3 * i + 0] = fast_tanh(o0);
    out[3 * i + 1] = fast_tanh(o1);
    out[3 * i + 2] = fast_tanh(o2);
}

extern "C" void kernel_launch(void* const* d_in, const int* in_sizes, int n_in,
                              void* d_out, int out_size, void* d_ws, size_t ws_size,
                              hipStream_t stream) {
    const float* dirs = (const float*)d_in[0];
    const float* grid = (const float*)d_in[1];
    const float* W1 = (const float*)d_in[2];
    const float* b1 = (const float*)d_in[3];
    const float* W2 = (const float*)d_in[4];
    const float* b2 = (const float*)d_in[5];
    const float* W3 = (const float*)d_in[6];
    const float* b3 = (const float*)d_in[7];
    const float* W4 = (const float*)d_in[8];
    const float* b4 = (const float*)d_in[9];
    float* out = (float*)d_out;

    const int n = in_sizes[0] / 3;
    const int nblocks = (n + BLK - 1) / BLK;
    const size_t need16 = (size_t)4 * 32768 * 4 * sizeof(__half);   // 1 MiB

    if (ws_size >= need16) {
        __half* g16 = (__half*)d_ws;
        hipLaunchKernelGGL(repack_kernel, dim3(512), dim3(256), 0, stream, grid, g16);
        hipLaunchKernelGGL(ngp_f16, dim3(nblocks), dim3(BLK), 0, stream,
                           dirs, g16, W1, b1, W2, b2, W3, b3, W4, b4, out, n);
    } else {
        hipLaunchKernelGGL(ngp_f32, dim3(nblocks), dim3(BLK), 0, stream,
                           dirs, grid, W1, b1, W2, b2, W3, b3, W4, b4, out, n);
    }
}